// Round 10
// baseline (340.792 us; speedup 1.0000x reference)
//
#include <hip/hip_runtime.h>
#include <hip/hip_bf16.h>

#define NN 512
#define MM (NN*NN)   // 262144 rows

typedef __attribute__((ext_vector_type(8))) unsigned short u16x8;
typedef __attribute__((ext_vector_type(4))) unsigned short u16x4;
typedef __attribute__((ext_vector_type(8))) __bf16 bf16x8;
typedef __attribute__((ext_vector_type(4))) float f32x4;

static __device__ __forceinline__ unsigned short f2bfi(float f) {
  return __builtin_bit_cast(unsigned short, __float2bfloat16(f));
}
static __device__ __forceinline__ float bf2f(unsigned short h) {
  return __uint_as_float(((unsigned int)h) << 16);
}
static __device__ __forceinline__ bf16x8 ldfrag(const unsigned short* p) {
  u16x8 v = *(const u16x8*)p;
  return __builtin_bit_cast(bf16x8, v);
}
static __device__ __forceinline__ float sigm(float x) {
  return __builtin_amdgcn_rcpf(1.0f + __expf(-x));
}

// ---------------- prep ------------------------------------------------------------------
// WT[n][k] rows 640..767 used by K3 (lu).  WTs: swizzled images for K1's 5 weights:
// WTs[gm][row][pchunk][j] = w[k][row] with k = (pchunk ^ (row&15))*8 + j  (chunk-XOR swizzle)
__global__ void prep_weights(const float* __restrict__ ga_w, const float* __restrict__ la_w,
                             const float* __restrict__ gb_w, const float* __restrict__ lb_w,
                             const float* __restrict__ g_w,  const float* __restrict__ lu_w,
                             unsigned short* __restrict__ WT, unsigned short* __restrict__ WTs) {
  int idx = blockIdx.x * 256 + threadIdx.x;   // 704*256 = 180224 = 98304 + 81920
  const float* tabs[6] = {ga_w, la_w, gb_w, lb_w, g_w, lu_w};
  if (idx < 98304) {
    int n = idx >> 7, k = idx & 127;
    int grp = n >> 7, cn = n & 127;
    WT[idx] = f2bfi(tabs[grp][k * 128 + cn]);
  } else {
    int id2 = idx - 98304;
    int gm = id2 >> 14;
    int r2 = id2 & 16383;
    int row = r2 >> 7, s = r2 & 127;
    int pchunk = s >> 3, j = s & 7;
    int k = ((pchunk ^ (row & 15)) << 3) + j;
    WTs[id2] = f2bfi(tabs[gm][k * 128 + row]);
  }
}

// ---------------- K1: fused LN + 5 projections -----------------------------------------
// grid M/128, 512 threads (8 waves as 4 row-groups x 2 col-groups; wave = 32 rows x 64 cols)
// Weights DMA'd via global_load_lds from pre-swizzled WTs; z held in af registers.
__global__ __launch_bounds__(512, 4) void k1_proj(
    const float* __restrict__ pair, const float* __restrict__ lng, const float* __restrict__ lnb,
    const unsigned short* __restrict__ WTs,
    const float* __restrict__ ga_b, const float* __restrict__ la_b,
    const float* __restrict__ gb_b, const float* __restrict__ lb_b,
    const float* __restrict__ g_b,
    unsigned short* __restrict__ a_t, unsigned short* __restrict__ b_t,
    unsigned short* __restrict__ g_buf) {
  __shared__ __align__(16) unsigned short W0[128 * 136];
  __shared__ __align__(16) unsigned short W1[128 * 136];
  const int t = threadIdx.x;
  const size_t m0 = (size_t)blockIdx.x * 128;
  const int wave = t >> 6, lane = t & 63, lrow = lane & 15, qk = lane >> 4;
  const int wr = wave >> 1, wc = wave & 1;

  // DMA-stage one 32KB weight image (linear dest; source pre-swizzled)
  auto stage_g = [&](unsigned short* buf, int gm) {
    const unsigned short* src = WTs + gm * 16384 + wave * 512 + lane * 8;
    unsigned short* dst = buf + wave * 512;   // wave-uniform base; HW adds lane*16B
#pragma unroll
    for (int cc = 0; cc < 4; ++cc)
      __builtin_amdgcn_global_load_lds((const void*)(src + cc * 4096),
                                       (void*)(dst + cc * 4096), 16, 0, 0);
  };

  stage_g(W1, 0);                                             // ga flies under LN

  // ---- LN: 128 rows -> W0 (bf16, [128][136] view) ----
  {
    const int row = t >> 2, q = t & 3;
    const float* pr = pair + (m0 + row) * 128 + q * 32;
    float vals[32];
    float s = 0.f, ss = 0.f;
#pragma unroll
    for (int it = 0; it < 8; ++it) {
      f32x4 v = *(const f32x4*)(pr + it * 4);
#pragma unroll
      for (int j = 0; j < 4; ++j) { float x = v[j]; vals[it * 4 + j] = x; s += x; ss += x * x; }
    }
    s += __shfl_xor(s, 1);  s += __shfl_xor(s, 2);
    ss += __shfl_xor(ss, 1); ss += __shfl_xor(ss, 2);
    const float mean = s * (1.f / 128.f);
    const float var  = ss * (1.f / 128.f) - mean * mean;
    const float rstd = rsqrtf(var + 1e-5f);
#pragma unroll
    for (int i = 0; i < 4; ++i) {
      u16x8 pk;
#pragma unroll
      for (int j = 0; j < 8; ++j) {
        int c = q * 32 + i * 8 + j;
        pk[j] = f2bfi((vals[i * 8 + j] - mean) * rstd * lng[c] + lnb[c]);
      }
      *(u16x8*)(W0 + row * 136 + q * 32 + i * 8) = pk;
    }
  }
  __syncthreads();                                            // b0: z in W0, ga in W1

  // hoist A-fragments: wave's 32 rows x all K (8 frags), from padded z view
  bf16x8 af[2][4];
#pragma unroll
  for (int mi = 0; mi < 2; ++mi)
#pragma unroll
    for (int ks = 0; ks < 4; ++ks)
      af[mi][ks] = ldfrag(W0 + (wr * 32 + mi * 16 + lrow) * 136 + ks * 32 + 8 * qk);
  __syncthreads();                                            // b1: z reads done, W0 reusable

  f32x4 accg[2][4], accl[2][4];
  // weight image read: row rr, logical chunk c=ks*4+qk, physical chunk = c ^ lrow
  auto run_gemm = [&](const unsigned short* buf, f32x4 (*acc)[4]) {
#pragma unroll
    for (int mi = 0; mi < 2; ++mi)
#pragma unroll
      for (int nt = 0; nt < 4; ++nt)
#pragma unroll
        for (int r = 0; r < 4; ++r) acc[mi][nt][r] = 0.f;
#pragma unroll
    for (int ks = 0; ks < 4; ++ks)
#pragma unroll
      for (int nt = 0; nt < 4; ++nt) {
        int rr = wc * 64 + nt * 16 + lrow;
        bf16x8 bv = ldfrag(buf + rr * 128 + (((ks * 4 + qk) ^ lrow) * 8));
        acc[0][nt] = __builtin_amdgcn_mfma_f32_16x16x32_bf16(af[0][ks], bv, acc[0][nt], 0, 0, 0);
        acc[1][nt] = __builtin_amdgcn_mfma_f32_16x16x32_bf16(af[1][ks], bv, acc[1][nt], 0, 0, 0);
      }
  };
  auto epi_ab = [&](unsigned short* buf, const float* gbias, const float* lbias) {
#pragma unroll
    for (int mi = 0; mi < 2; ++mi)
#pragma unroll
      for (int nt = 0; nt < 4; ++nt) {
        int col = wc * 64 + nt * 16 + lrow;
        float bg = gbias[col], bl = lbias[col];
        u16x4 pk;
#pragma unroll
        for (int r = 0; r < 4; ++r)
          pk[r] = f2bfi(sigm(accg[mi][nt][r] + bg) * (accl[mi][nt][r] + bl));
        *(u16x4*)(buf + col * 136 + wr * 32 + mi * 16 + qk * 4) = pk;
      }
  };
  auto wout = [&](unsigned short* dst, const unsigned short* buf) {
#pragma unroll
    for (int it = 0; it < 4; ++it) {
      int idx = it * 512 + t;
      int col = idx >> 4, i = idx & 15;
      *(u16x8*)(dst + (size_t)col * MM + m0 + i * 8) = *(const u16x8*)(buf + col * 136 + i * 8);
    }
  };

  // ph2: GEMM ga(W1); DMA la -> W0
  run_gemm(W1, accg);
  stage_g(W0, 1);
  __syncthreads();                                            // b2
  // ph3: GEMM la(W0); DMA gb -> W1
  run_gemm(W0, accl);
  stage_g(W1, 2);
  __syncthreads();                                            // b3
  // ph4: epilogue a -> W0 (transposed [col][row] view)
  epi_ab(W0, ga_b, la_b);
  __syncthreads();                                            // b4
  // ph5: write a_t from W0; GEMM gb(W1)
  wout(a_t, W0);
  run_gemm(W1, accg);
  __syncthreads();                                            // b5
  // ph6: DMA lb -> W0, g -> W1
  stage_g(W0, 3);
  stage_g(W1, 4);
  __syncthreads();                                            // b6
  // ph7: GEMM lb(W0)
  run_gemm(W0, accl);
  __syncthreads();                                            // b7
  // ph8: epilogue b -> W0; GEMM g(W1)
  epi_ab(W0, gb_b, lb_b);
  run_gemm(W1, accg);
  __syncthreads();                                            // b8
  // ph9: write b_t; stage g row-major in W1 ([128][136] view)
  wout(b_t, W0);
#pragma unroll
  for (int mi = 0; mi < 2; ++mi)
#pragma unroll
    for (int nt = 0; nt < 4; ++nt) {
      int col = wc * 64 + nt * 16 + lrow;
      float bg = g_b[col];
#pragma unroll
      for (int r = 0; r < 4; ++r)
        W1[(wr * 32 + mi * 16 + qk * 4 + r) * 136 + col] = f2bfi(sigm(accg[mi][nt][r] + bg));
    }
  __syncthreads();                                            // b9
  // ph10: coalesced g copy-out
#pragma unroll
  for (int it = 0; it < 4; ++it) {
    int idx = it * 512 + t;
    int mr = idx >> 4, off = (idx & 15) * 8;
    *(u16x8*)(g_buf + (m0 + mr) * 128 + off) = *(const u16x8*)(W1 + mr * 136 + off);
  }
}

// ---------------- K2: channel-batched NT GEMM (R6 proven, direct stores) ---------------
__global__ __launch_bounds__(256) void k2_einsum(
    const unsigned short* __restrict__ a_t, const unsigned short* __restrict__ b_t,
    unsigned short* __restrict__ up_t) {
  __shared__ __align__(16) unsigned short lds[20480];
  const int t = threadIdx.x;
  const int wid = (blockIdx.x & 7) * 256 + (blockIdx.x >> 3);
  const int c = wid >> 4;
  const int i0 = ((wid >> 2) & 3) * 128, j0 = (wid & 3) * 128;
  const unsigned short* Ag = a_t + (size_t)c * MM + (size_t)i0 * 512;
  const unsigned short* Bg = b_t + (size_t)c * MM + (size_t)j0 * 512;
  const int wave = t >> 6, lane = t & 63, wr = wave >> 1, wc = wave & 1;
  const int lrow = lane & 15, qk = lane >> 4;
  const int srow = t >> 2, sq = t & 3;
  f32x4 acc[4][4];
#pragma unroll
  for (int i = 0; i < 4; ++i)
#pragma unroll
    for (int j = 0; j < 4; ++j)
#pragma unroll
      for (int r = 0; r < 4; ++r) acc[i][j][r] = 0.f;

  u16x8 ra[2], rb[2];
  auto tile_ld = [&](int k0) {
#pragma unroll
    for (int h = 0; h < 2; ++h) {
      int row = h * 64 + srow;
      ra[h] = *(const u16x8*)(Ag + (size_t)row * 512 + k0 + sq * 8);
      rb[h] = *(const u16x8*)(Bg + (size_t)row * 512 + k0 + sq * 8);
    }
  };
  auto tile_st = [&](int buf) {
    unsigned short* sA = lds + buf * 5120;
    unsigned short* sB = lds + 10240 + buf * 5120;
#pragma unroll
    for (int h = 0; h < 2; ++h) {
      int row = h * 64 + srow;
      *(u16x8*)(sA + row * 40 + sq * 8) = ra[h];
      *(u16x8*)(sB + row * 40 + sq * 8) = rb[h];
    }
  };

  tile_ld(0);
  tile_st(0);
  __syncthreads();
  int cur = 0;
  for (int ks = 0; ks < 16; ++ks) {
    if (ks < 15) tile_ld((ks + 1) * 32);
    const unsigned short* sA = lds + cur * 5120;
    const unsigned short* sB = lds + 10240 + cur * 5120;
    bf16x8 afr[4], bv[4];
#pragma unroll
    for (int mt = 0; mt < 4; ++mt)
      afr[mt] = ldfrag(sA + (wr * 64 + mt * 16 + lrow) * 40 + 8 * qk);
#pragma unroll
    for (int nt = 0; nt < 4; ++nt)
      bv[nt] = ldfrag(sB + (wc * 64 + nt * 16 + lrow) * 40 + 8 * qk);
#pragma unroll
    for (int mt = 0; mt < 4; ++mt)
#pragma unroll
      for (int nt = 0; nt < 4; ++nt)
        acc[mt][nt] = __builtin_amdgcn_mfma_f32_16x16x32_bf16(afr[mt], bv[nt], acc[mt][nt], 0, 0, 0);
    if (ks < 15) tile_st(cur ^ 1);
    __syncthreads();
    cur ^= 1;
  }
  unsigned short* up = up_t + (size_t)c * MM;
#pragma unroll
  for (int mt = 0; mt < 4; ++mt)
#pragma unroll
    for (int nt = 0; nt < 4; ++nt) {
      int col = j0 + wc * 64 + nt * 16 + lrow;
#pragma unroll
      for (int r = 0; r < 4; ++r) {
        int row = i0 + wr * 64 + mt * 16 + qk * 4 + r;
        up[(size_t)row * 512 + col] = f2bfi(acc[mt][nt][r]);
      }
    }
}

// ---------------- K3: LN(update) @ lu_w + lu_b, * g -> out (R6 proven, unchanged) ------
__global__ __launch_bounds__(256) void k3_final(
    const unsigned short* __restrict__ up_t, const unsigned short* __restrict__ g_buf,
    const unsigned short* __restrict__ WT,
    const float* __restrict__ lnug, const float* __restrict__ lnub,
    const float* __restrict__ lu_b, float* __restrict__ out) {
  __shared__ __align__(16) unsigned short sU[64 * 138];
  __shared__ __align__(16) unsigned short sA[64 * 136];
  __shared__ __align__(16) unsigned short sB[128 * 136];
  const int t = threadIdx.x;
  const size_t m0 = (size_t)blockIdx.x * 64;
#pragma unroll
  for (int it = 0; it < 4; ++it) {
    int idx = it * 256 + t;
    int c = idx >> 3, m8 = (idx & 7) * 8;
    u16x8 v = *(const u16x8*)(up_t + (size_t)c * MM + m0 + m8);
#pragma unroll
    for (int j = 0; j < 8; ++j) sU[(m8 + j) * 138 + c] = v[j];
  }
#pragma unroll
  for (int it = 0; it < 8; ++it) {
    int idx = it * 256 + t;
    int n = idx >> 4, off = (idx & 15) * 8;
    *(u16x8*)(sB + n * 136 + off) = *(const u16x8*)(WT + (size_t)(640 + n) * 128 + off);
  }
  __syncthreads();
  {
    const int row = t >> 2, q = t & 3;
    float vals[32]; float s = 0.f, ss = 0.f;
#pragma unroll
    for (int jj = 0; jj < 32; ++jj) {
      int cc = q + jj * 4;
      float x = bf2f(sU[row * 138 + cc]);
      vals[jj] = x; s += x; ss += x * x;
    }
    s += __shfl_xor(s, 1);  s += __shfl_xor(s, 2);
    ss += __shfl_xor(ss, 1); ss += __shfl_xor(ss, 2);
    float mean = s * (1.f / 128.f);
    float var  = ss * (1.f / 128.f) - mean * mean;
    float rstd = rsqrtf(var + 1e-5f);
#pragma unroll
    for (int jj = 0; jj < 32; ++jj) {
      int cc = q + jj * 4;
      float zn = (vals[jj] - mean) * rstd * lnug[cc] + lnub[cc];
      sA[row * 136 + cc] = f2bfi(zn);
    }
  }
  __syncthreads();
  const int wave = t >> 6, lane = t & 63, lrow = lane & 15, qk = lane >> 4;
  f32x4 acc[8];
#pragma unroll
  for (int i = 0; i < 8; ++i)
#pragma unroll
    for (int r = 0; r < 4; ++r) acc[i][r] = 0.f;
#pragma unroll
  for (int ks = 0; ks < 4; ++ks) {
    int k0 = ks * 32;
    bf16x8 af = ldfrag(sA + (wave * 16 + lrow) * 136 + k0 + 8 * qk);
#pragma unroll
    for (int nt = 0; nt < 8; ++nt) {
      bf16x8 bv = ldfrag(sB + (nt * 16 + lrow) * 136 + k0 + 8 * qk);
      acc[nt] = __builtin_amdgcn_mfma_f32_16x16x32_bf16(af, bv, acc[nt], 0, 0, 0);
    }
  }
#pragma unroll
  for (int nt = 0; nt < 8; ++nt) {
    int e = nt * 16 + lrow;
    float bb = lu_b[e];
#pragma unroll
    for (int r = 0; r < 4; ++r) {
      size_t m = m0 + wave * 16 + qk * 4 + r;
      float lin = acc[nt][r] + bb;
      float gv = bf2f(g_buf[m * 128 + e]);
      out[m * 128 + e] = gv * lin;
    }
  }
}

extern "C" void kernel_launch(void* const* d_in, const int* in_sizes, int n_in,
                              void* d_out, int out_size, void* d_ws, size_t ws_size,
                              hipStream_t stream) {
  const float* pair = (const float*)d_in[0];
  const float* lng  = (const float*)d_in[1];
  const float* lnb  = (const float*)d_in[2];
  const float* ga_w = (const float*)d_in[3];
  const float* ga_b = (const float*)d_in[4];
  const float* la_w = (const float*)d_in[5];
  const float* la_b = (const float*)d_in[6];
  const float* gb_w = (const float*)d_in[7];
  const float* gb_b = (const float*)d_in[8];
  const float* lb_w = (const float*)d_in[9];
  const float* lb_b = (const float*)d_in[10];
  const float* g_w  = (const float*)d_in[11];
  const float* g_b  = (const float*)d_in[12];
  const float* lnug = (const float*)d_in[13];
  const float* lnub = (const float*)d_in[14];
  const float* lu_w = (const float*)d_in[15];
  const float* lu_b = (const float*)d_in[16];
  float* out = (float*)d_out;

  char* ws = (char*)d_ws;
  unsigned short* WT    = (unsigned short*)(ws);                  // 196608 B
  unsigned short* WTs   = (unsigned short*)(ws + 196608ull);      // 163840 B
  unsigned short* a_t   = (unsigned short*)(ws + 360448ull);      // 128*M*2
  unsigned short* b_t   = (unsigned short*)(ws + 67469312ull);    // 128*M*2
  unsigned short* g_buf = (unsigned short*)(ws + 134578176ull);   // M*128*2
  unsigned short* up_t  = (unsigned short*)(ws + 201687040ull);   // 128*M*2 (end ~268.8 MB)

  hipLaunchKernelGGL(prep_weights, dim3(704), dim3(256), 0, stream,
                     ga_w, la_w, gb_w, lb_w, g_w, lu_w, WT, WTs);
  hipLaunchKernelGGL(k1_proj, dim3(2048), dim3(512), 0, stream,
                     pair, lng, lnb, WTs, ga_b, la_b, gb_b, lb_b, g_b, a_t, b_t, g_buf);
  hipLaunchKernelGGL(k2_einsum, dim3(2048), dim3(256), 0, stream, a_t, b_t, up_t);
  hipLaunchKernelGGL(k3_final, dim3(4096), dim3(256), 0, stream,
                     up_t, g_buf, WT, lnug, lnub, lu_b, out);
}

// Round 11
// 287.511 us; speedup vs baseline: 1.1853x; 1.1853x over previous
//
#include <hip/hip_runtime.h>
#include <hip/hip_bf16.h>

#define NN 512
#define MM (NN*NN)   // 262144 rows

typedef __attribute__((ext_vector_type(8))) unsigned short u16x8;
typedef __attribute__((ext_vector_type(4))) unsigned short u16x4;
typedef __attribute__((ext_vector_type(8))) __bf16 bf16x8;
typedef __attribute__((ext_vector_type(4))) float f32x4;

static __device__ __forceinline__ unsigned short f2bfi(float f) {
  return __builtin_bit_cast(unsigned short, __float2bfloat16(f));
}
static __device__ __forceinline__ float bf2f(unsigned short h) {
  return __uint_as_float(((unsigned int)h) << 16);
}
static __device__ __forceinline__ bf16x8 ldfrag(const unsigned short* p) {
  u16x8 v = *(const u16x8*)p;
  return __builtin_bit_cast(bf16x8, v);
}
static __device__ __forceinline__ float sigm(float x) {
  return __builtin_amdgcn_rcpf(1.0f + __expf(-x));
}

// ---------------- prep: WT[n][k] (bf16), n: [ga|la|gb|lb|g|lu] x 128 cols, k = 128 ----
__global__ void prep_weights(const float* __restrict__ ga_w, const float* __restrict__ la_w,
                             const float* __restrict__ gb_w, const float* __restrict__ lb_w,
                             const float* __restrict__ g_w,  const float* __restrict__ lu_w,
                             unsigned short* __restrict__ WT) {
  int idx = blockIdx.x * 256 + threadIdx.x;
  if (idx >= 768 * 128) return;
  int n = idx >> 7;
  int k = idx & 127;
  int grp = n >> 7, cn = n & 127;
  const float* tabs[6] = {ga_w, la_w, gb_w, lb_w, g_w, lu_w};
  WT[idx] = f2bfi(tabs[grp][k * 128 + cn]);
}

// ---------------- K1: fused LN + 5 projections (R6 config + swizzled epi staging) ------
__global__ __launch_bounds__(512, 4) void k1_proj(
    const float* __restrict__ pair, const float* __restrict__ lng, const float* __restrict__ lnb,
    const unsigned short* __restrict__ WT,
    const float* __restrict__ ga_b, const float* __restrict__ la_b,
    const float* __restrict__ gb_b, const float* __restrict__ lb_b,
    const float* __restrict__ g_b,
    unsigned short* __restrict__ a_t, unsigned short* __restrict__ b_t,
    unsigned short* __restrict__ g_buf) {
  __shared__ __align__(16) unsigned short W0[128 * 136];
  __shared__ __align__(16) unsigned short W1[128 * 136];
  const int t = threadIdx.x;
  const size_t m0 = (size_t)blockIdx.x * 128;
  const int wave = t >> 6, lane = t & 63, lrow = lane & 15, qk = lane >> 4;
  const int rbase = t >> 4, off_ = (t & 15) * 8;

  u16x8 rga[4], rla[4], rgb[4], rlb[4], rg[4];
  auto stage_ld = [&](u16x8* r, int base) {
#pragma unroll
    for (int it = 0; it < 4; ++it)
      r[it] = *(const u16x8*)(WT + (size_t)(base + it * 32 + rbase) * 128 + off_);
  };
  auto stage_st = [&](unsigned short* buf, const u16x8* r) {
#pragma unroll
    for (int it = 0; it < 4; ++it)
      *(u16x8*)(buf + (it * 32 + rbase) * 136 + off_) = r[it];
  };

  stage_ld(rga, 0);
  stage_ld(rla, 128);

  {
    const int row = t >> 2, q = t & 3;
    const float* pr = pair + (m0 + row) * 128 + q * 32;
    float vals[32];
    float s = 0.f, ss = 0.f;
#pragma unroll
    for (int it = 0; it < 8; ++it) {
      f32x4 v = *(const f32x4*)(pr + it * 4);
#pragma unroll
      for (int j = 0; j < 4; ++j) { float x = v[j]; vals[it * 4 + j] = x; s += x; ss += x * x; }
    }
    s += __shfl_xor(s, 1);  s += __shfl_xor(s, 2);
    ss += __shfl_xor(ss, 1); ss += __shfl_xor(ss, 2);
    const float mean = s * (1.f / 128.f);
    const float var  = ss * (1.f / 128.f) - mean * mean;
    const float rstd = rsqrtf(var + 1e-5f);
#pragma unroll
    for (int i = 0; i < 4; ++i) {
      u16x8 pk;
#pragma unroll
      for (int j = 0; j < 8; ++j) {
        int c = q * 32 + i * 8 + j;
        pk[j] = f2bfi((vals[i * 8 + j] - mean) * rstd * lng[c] + lnb[c]);
      }
      *(u16x8*)(W0 + row * 136 + q * 32 + i * 8) = pk;
    }
  }
  __syncthreads();                                            // b0

  bf16x8 af[4];
  f32x4 accg[8], accl[8];
  auto run_gemm = [&](const unsigned short* buf, f32x4* acc) {
#pragma unroll
    for (int nt = 0; nt < 8; ++nt)
#pragma unroll
      for (int r = 0; r < 4; ++r) acc[nt][r] = 0.f;
#pragma unroll
    for (int ks = 0; ks < 4; ++ks)
#pragma unroll
      for (int nt = 0; nt < 8; ++nt) {
        bf16x8 bv = ldfrag(buf + (nt * 16 + lrow) * 136 + ks * 32 + 8 * qk);
        acc[nt] = __builtin_amdgcn_mfma_f32_16x16x32_bf16(af[ks], bv, acc[nt], 0, 0, 0);
      }
  };
  // epilogue staging: transposed [col][row-bytes], XOR-swizzled (bits 5-7 ^ col&7)
  // write 8B at S ^ ((col&7)<<5); read back 16B at (i*16) ^ ((col&7)<<5). Bijective
  // within each col's 256B region; breaks the 8-way bank conflict of stride-272 cols.
  auto epi_ab = [&](unsigned short* buf, const float* gbias, const float* lbias) {
    const int S = (wave * 16 + qk * 4) * 2;
#pragma unroll
    for (int nt = 0; nt < 8; ++nt) {
      int col = nt * 16 + lrow;
      float bg = gbias[col], bl = lbias[col];
      u16x4 pk;
#pragma unroll
      for (int r = 0; r < 4; ++r)
        pk[r] = f2bfi(sigm(accg[nt][r] + bg) * (accl[nt][r] + bl));
      *(u16x4*)((char*)buf + col * 272 + (S ^ ((col & 7) << 5))) = pk;
    }
  };
  auto wout = [&](unsigned short* dst, const unsigned short* buf) {
#pragma unroll
    for (int it = 0; it < 4; ++it) {
      int idx = it * 512 + t;
      int col = idx >> 4, i = idx & 15;
      u16x8 v = *(const u16x8*)((const char*)buf + col * 272 + ((i * 16) ^ ((col & 7) << 5)));
      *(u16x8*)(dst + (size_t)col * MM + m0 + i * 8) = v;
    }
  };

#pragma unroll
  for (int ks = 0; ks < 4; ++ks)
    af[ks] = ldfrag(W0 + (wave * 16 + lrow) * 136 + ks * 32 + 8 * qk);
  stage_st(W1, rga);
  stage_ld(rgb, 256);
  __syncthreads();                                            // b1
  run_gemm(W1, accg);
  stage_st(W0, rla);
  stage_ld(rlb, 384);
  __syncthreads();                                            // b2
  run_gemm(W0, accl);
  stage_st(W1, rgb);
  stage_ld(rg, 512);
  __syncthreads();                                            // b3
  epi_ab(W0, ga_b, la_b);
  __syncthreads();                                            // b4
  wout(a_t, W0);
  run_gemm(W1, accg);
  __syncthreads();                                            // b5
  stage_st(W0, rlb);
  stage_st(W1, rg);
  __syncthreads();                                            // b6
  run_gemm(W0, accl);
  __syncthreads();                                            // b7
  epi_ab(W0, gb_b, lb_b);
  run_gemm(W1, accg);
  __syncthreads();                                            // b8
  wout(b_t, W0);
#pragma unroll
  for (int nt = 0; nt < 8; ++nt) {
    int col = nt * 16 + lrow;
    float bg = g_b[col];
#pragma unroll
    for (int r = 0; r < 4; ++r)
      W1[(wave * 16 + qk * 4 + r) * 136 + col] = f2bfi(sigm(accg[nt][r] + bg));
  }
  __syncthreads();                                            // b9
#pragma unroll
  for (int it = 0; it < 4; ++it) {
    int idx = it * 512 + t;
    int mr = idx >> 4, off = (idx & 15) * 8;
    *(u16x8*)(g_buf + (m0 + mr) * 128 + off) = *(const u16x8*)(W1 + mr * 136 + off);
  }
}

// ---------------- K2: channel-batched NT GEMM (R6 proven, direct stores) ---------------
__global__ __launch_bounds__(256) void k2_einsum(
    const unsigned short* __restrict__ a_t, const unsigned short* __restrict__ b_t,
    unsigned short* __restrict__ up_t) {
  __shared__ __align__(16) unsigned short lds[20480];
  const int t = threadIdx.x;
  const int wid = (blockIdx.x & 7) * 256 + (blockIdx.x >> 3);
  const int c = wid >> 4;
  const int i0 = ((wid >> 2) & 3) * 128, j0 = (wid & 3) * 128;
  const unsigned short* Ag = a_t + (size_t)c * MM + (size_t)i0 * 512;
  const unsigned short* Bg = b_t + (size_t)c * MM + (size_t)j0 * 512;
  const int wave = t >> 6, lane = t & 63, wr = wave >> 1, wc = wave & 1;
  const int lrow = lane & 15, qk = lane >> 4;
  const int srow = t >> 2, sq = t & 3;
  f32x4 acc[4][4];
#pragma unroll
  for (int i = 0; i < 4; ++i)
#pragma unroll
    for (int j = 0; j < 4; ++j)
#pragma unroll
      for (int r = 0; r < 4; ++r) acc[i][j][r] = 0.f;

  u16x8 ra[2], rb[2];
  auto tile_ld = [&](int k0) {
#pragma unroll
    for (int h = 0; h < 2; ++h) {
      int row = h * 64 + srow;
      ra[h] = *(const u16x8*)(Ag + (size_t)row * 512 + k0 + sq * 8);
      rb[h] = *(const u16x8*)(Bg + (size_t)row * 512 + k0 + sq * 8);
    }
  };
  auto tile_st = [&](int buf) {
    unsigned short* sA = lds + buf * 5120;
    unsigned short* sB = lds + 10240 + buf * 5120;
#pragma unroll
    for (int h = 0; h < 2; ++h) {
      int row = h * 64 + srow;
      *(u16x8*)(sA + row * 40 + sq * 8) = ra[h];
      *(u16x8*)(sB + row * 40 + sq * 8) = rb[h];
    }
  };

  tile_ld(0);
  tile_st(0);
  __syncthreads();
  int cur = 0;
  for (int ks = 0; ks < 16; ++ks) {
    if (ks < 15) tile_ld((ks + 1) * 32);
    const unsigned short* sA = lds + cur * 5120;
    const unsigned short* sB = lds + 10240 + cur * 5120;
    bf16x8 afr[4], bv[4];
#pragma unroll
    for (int mt = 0; mt < 4; ++mt)
      afr[mt] = ldfrag(sA + (wr * 64 + mt * 16 + lrow) * 40 + 8 * qk);
#pragma unroll
    for (int nt = 0; nt < 4; ++nt)
      bv[nt] = ldfrag(sB + (wc * 64 + nt * 16 + lrow) * 40 + 8 * qk);
#pragma unroll
    for (int mt = 0; mt < 4; ++mt)
#pragma unroll
      for (int nt = 0; nt < 4; ++nt)
        acc[mt][nt] = __builtin_amdgcn_mfma_f32_16x16x32_bf16(afr[mt], bv[nt], acc[mt][nt], 0, 0, 0);
    if (ks < 15) tile_st(cur ^ 1);
    __syncthreads();
    cur ^= 1;
  }
  unsigned short* up = up_t + (size_t)c * MM;
#pragma unroll
  for (int mt = 0; mt < 4; ++mt)
#pragma unroll
    for (int nt = 0; nt < 4; ++nt) {
      int col = j0 + wc * 64 + nt * 16 + lrow;
#pragma unroll
      for (int r = 0; r < 4; ++r) {
        int row = i0 + wr * 64 + mt * 16 + qk * 4 + r;
        up[(size_t)row * 512 + col] = f2bfi(acc[mt][nt][r]);
      }
    }
}

// ---------------- K3: LN(update) @ lu_w + lu_b, * g -> out (R6 proven, unchanged) ------
__global__ __launch_bounds__(256) void k3_final(
    const unsigned short* __restrict__ up_t, const unsigned short* __restrict__ g_buf,
    const unsigned short* __restrict__ WT,
    const float* __restrict__ lnug, const float* __restrict__ lnub,
    const float* __restrict__ lu_b, float* __restrict__ out) {
  __shared__ __align__(16) unsigned short sU[64 * 138];
  __shared__ __align__(16) unsigned short sA[64 * 136];
  __shared__ __align__(16) unsigned short sB[128 * 136];
  const int t = threadIdx.x;
  const size_t m0 = (size_t)blockIdx.x * 64;
#pragma unroll
  for (int it = 0; it < 4; ++it) {
    int idx = it * 256 + t;
    int c = idx >> 3, m8 = (idx & 7) * 8;
    u16x8 v = *(const u16x8*)(up_t + (size_t)c * MM + m0 + m8);
#pragma unroll
    for (int j = 0; j < 8; ++j) sU[(m8 + j) * 138 + c] = v[j];
  }
#pragma unroll
  for (int it = 0; it < 8; ++it) {
    int idx = it * 256 + t;
    int n = idx >> 4, off = (idx & 15) * 8;
    *(u16x8*)(sB + n * 136 + off) = *(const u16x8*)(WT + (size_t)(640 + n) * 128 + off);
  }
  __syncthreads();
  {
    const int row = t >> 2, q = t & 3;
    float vals[32]; float s = 0.f, ss = 0.f;
#pragma unroll
    for (int jj = 0; jj < 32; ++jj) {
      int cc = q + jj * 4;
      float x = bf2f(sU[row * 138 + cc]);
      vals[jj] = x; s += x; ss += x * x;
    }
    s += __shfl_xor(s, 1);  s += __shfl_xor(s, 2);
    ss += __shfl_xor(ss, 1); ss += __shfl_xor(ss, 2);
    float mean = s * (1.f / 128.f);
    float var  = ss * (1.f / 128.f) - mean * mean;
    float rstd = rsqrtf(var + 1e-5f);
#pragma unroll
    for (int jj = 0; jj < 32; ++jj) {
      int cc = q + jj * 4;
      float zn = (vals[jj] - mean) * rstd * lnug[cc] + lnub[cc];
      sA[row * 136 + cc] = f2bfi(zn);
    }
  }
  __syncthreads();
  const int wave = t >> 6, lane = t & 63, lrow = lane & 15, qk = lane >> 4;
  f32x4 acc[8];
#pragma unroll
  for (int i = 0; i < 8; ++i)
#pragma unroll
    for (int r = 0; r < 4; ++r) acc[i][r] = 0.f;
#pragma unroll
  for (int ks = 0; ks < 4; ++ks) {
    int k0 = ks * 32;
    bf16x8 af = ldfrag(sA + (wave * 16 + lrow) * 136 + k0 + 8 * qk);
#pragma unroll
    for (int nt = 0; nt < 8; ++nt) {
      bf16x8 bv = ldfrag(sB + (nt * 16 + lrow) * 136 + k0 + 8 * qk);
      acc[nt] = __builtin_amdgcn_mfma_f32_16x16x32_bf16(af, bv, acc[nt], 0, 0, 0);
    }
  }
#pragma unroll
  for (int nt = 0; nt < 8; ++nt) {
    int e = nt * 16 + lrow;
    float bb = lu_b[e];
#pragma unroll
    for (int r = 0; r < 4; ++r) {
      size_t m = m0 + wave * 16 + qk * 4 + r;
      float lin = acc[nt][r] + bb;
      float gv = bf2f(g_buf[m * 128 + e]);
      out[m * 128 + e] = gv * lin;
    }
  }
}

extern "C" void kernel_launch(void* const* d_in, const int* in_sizes, int n_in,
                              void* d_out, int out_size, void* d_ws, size_t ws_size,
                              hipStream_t stream) {
  const float* pair = (const float*)d_in[0];
  const float* lng  = (const float*)d_in[1];
  const float* lnb  = (const float*)d_in[2];
  const float* ga_w = (const float*)d_in[3];
  const float* ga_b = (const float*)d_in[4];
  const float* la_w = (const float*)d_in[5];
  const float* la_b = (const float*)d_in[6];
  const float* gb_w = (const float*)d_in[7];
  const float* gb_b = (const float*)d_in[8];
  const float* lb_w = (const float*)d_in[9];
  const float* lb_b = (const float*)d_in[10];
  const float* g_w  = (const float*)d_in[11];
  const float* g_b  = (const float*)d_in[12];
  const float* lnug = (const float*)d_in[13];
  const float* lnub = (const float*)d_in[14];
  const float* lu_w = (const float*)d_in[15];
  const float* lu_b = (const float*)d_in[16];
  float* out = (float*)d_out;

  char* ws = (char*)d_ws;
  unsigned short* WT    = (unsigned short*)(ws);                  // 196608 B
  unsigned short* a_t   = (unsigned short*)(ws + 196608ull);      // 128*M*2
  unsigned short* b_t   = (unsigned short*)(ws + 67305472ull);    // 128*M*2
  unsigned short* g_buf = (unsigned short*)(ws + 134414336ull);   // M*128*2
  unsigned short* up_t  = (unsigned short*)(ws + 201523200ull);   // 128*M*2

  hipLaunchKernelGGL(prep_weights, dim3(384), dim3(256), 0, stream,
                     ga_w, la_w, gb_w, lb_w, g_w, lu_w, WT);
  hipLaunchKernelGGL(k1_proj, dim3(2048), dim3(512), 0, stream,
                     pair, lng, lnb, WT, ga_b, la_b, gb_b, lb_b, g_b, a_t, b_t, g_buf);
  hipLaunchKernelGGL(k2_einsum, dim3(2048), dim3(256), 0, stream, a_t, b_t, up_t);
  hipLaunchKernelGGL(k3_final, dim3(4096), dim3(256), 0, stream,
                     up_t, g_buf, WT, lnug, lnub, lu_b, out);
}

// Round 12
// 281.638 us; speedup vs baseline: 1.2100x; 1.0209x over previous
//
#include <hip/hip_runtime.h>
#include <hip/hip_bf16.h>

#define NN 512
#define MM (NN*NN)   // 262144 rows

typedef __attribute__((ext_vector_type(8))) unsigned short u16x8;
typedef __attribute__((ext_vector_type(4))) unsigned short u16x4;
typedef __attribute__((ext_vector_type(8))) __bf16 bf16x8;
typedef __attribute__((ext_vector_type(4))) float f32x4;

static __device__ __forceinline__ unsigned short f2bfi(float f) {
  return __builtin_bit_cast(unsigned short, __float2bfloat16(f));
}
static __device__ __forceinline__ float bf2f(unsigned short h) {
  return __uint_as_float(((unsigned int)h) << 16);
}
static __device__ __forceinline__ bf16x8 ldfrag(const unsigned short* p) {
  u16x8 v = *(const u16x8*)p;
  return __builtin_bit_cast(bf16x8, v);
}
static __device__ __forceinline__ float sigm(float x) {
  return __builtin_amdgcn_rcpf(1.0f + __expf(-x));
}
// LDS-only barrier: drains ds ops (lgkmcnt) but leaves global loads/stores in flight.
// All producer->consumer edges across these barriers are ds_write -> ds_read; no
// global_load_lds is used, so vmcnt(0) drain (what __syncthreads emits) is not needed.
static __device__ __forceinline__ void bar_lds() {
  asm volatile("s_waitcnt lgkmcnt(0)" ::: "memory");
  __builtin_amdgcn_s_barrier();
}

// ---------------- prep: WT[n][k] (bf16), n: [ga|la|gb|lb|g|lu] x 128 cols, k = 128 ----
__global__ void prep_weights(const float* __restrict__ ga_w, const float* __restrict__ la_w,
                             const float* __restrict__ gb_w, const float* __restrict__ lb_w,
                             const float* __restrict__ g_w,  const float* __restrict__ lu_w,
                             unsigned short* __restrict__ WT) {
  int idx = blockIdx.x * 256 + threadIdx.x;
  if (idx >= 768 * 128) return;
  int n = idx >> 7;
  int k = idx & 127;
  int grp = n >> 7, cn = n & 127;
  const float* tabs[6] = {ga_w, la_w, gb_w, lb_w, g_w, lu_w};
  WT[idx] = f2bfi(tabs[grp][k * 128 + cn]);
}

// ---------------- K1: fused LN + 5 projections (R6 config + lgkm-only barriers) --------
__global__ __launch_bounds__(512, 4) void k1_proj(
    const float* __restrict__ pair, const float* __restrict__ lng, const float* __restrict__ lnb,
    const unsigned short* __restrict__ WT,
    const float* __restrict__ ga_b, const float* __restrict__ la_b,
    const float* __restrict__ gb_b, const float* __restrict__ lb_b,
    const float* __restrict__ g_b,
    unsigned short* __restrict__ a_t, unsigned short* __restrict__ b_t,
    unsigned short* __restrict__ g_buf) {
  __shared__ __align__(16) unsigned short W0[128 * 136];
  __shared__ __align__(16) unsigned short W1[128 * 136];
  const int t = threadIdx.x;
  const size_t m0 = (size_t)blockIdx.x * 128;
  const int wave = t >> 6, lane = t & 63, lrow = lane & 15, qk = lane >> 4;
  const int rbase = t >> 4, off_ = (t & 15) * 8;

  u16x8 rga[4], rla[4], rgb[4], rlb[4], rg[4];
  auto stage_ld = [&](u16x8* r, int base) {
#pragma unroll
    for (int it = 0; it < 4; ++it)
      r[it] = *(const u16x8*)(WT + (size_t)(base + it * 32 + rbase) * 128 + off_);
  };
  auto stage_st = [&](unsigned short* buf, const u16x8* r) {
#pragma unroll
    for (int it = 0; it < 4; ++it)
      *(u16x8*)(buf + (it * 32 + rbase) * 136 + off_) = r[it];
  };

  stage_ld(rga, 0);
  stage_ld(rla, 128);

  {
    const int row = t >> 2, q = t & 3;
    const float* pr = pair + (m0 + row) * 128 + q * 32;
    float vals[32];
    float s = 0.f, ss = 0.f;
#pragma unroll
    for (int it = 0; it < 8; ++it) {
      f32x4 v = *(const f32x4*)(pr + it * 4);
#pragma unroll
      for (int j = 0; j < 4; ++j) { float x = v[j]; vals[it * 4 + j] = x; s += x; ss += x * x; }
    }
    s += __shfl_xor(s, 1);  s += __shfl_xor(s, 2);
    ss += __shfl_xor(ss, 1); ss += __shfl_xor(ss, 2);
    const float mean = s * (1.f / 128.f);
    const float var  = ss * (1.f / 128.f) - mean * mean;
    const float rstd = rsqrtf(var + 1e-5f);
#pragma unroll
    for (int i = 0; i < 4; ++i) {
      u16x8 pk;
#pragma unroll
      for (int j = 0; j < 8; ++j) {
        int c = q * 32 + i * 8 + j;
        pk[j] = f2bfi((vals[i * 8 + j] - mean) * rstd * lng[c] + lnb[c]);
      }
      *(u16x8*)(W0 + row * 136 + q * 32 + i * 8) = pk;
    }
  }
  bar_lds();                                                  // b0

  bf16x8 af[4];
  f32x4 accg[8], accl[8];
  auto run_gemm = [&](const unsigned short* buf, f32x4* acc) {
#pragma unroll
    for (int nt = 0; nt < 8; ++nt)
#pragma unroll
      for (int r = 0; r < 4; ++r) acc[nt][r] = 0.f;
#pragma unroll
    for (int ks = 0; ks < 4; ++ks)
#pragma unroll
      for (int nt = 0; nt < 8; ++nt) {
        bf16x8 bv = ldfrag(buf + (nt * 16 + lrow) * 136 + ks * 32 + 8 * qk);
        acc[nt] = __builtin_amdgcn_mfma_f32_16x16x32_bf16(af[ks], bv, acc[nt], 0, 0, 0);
      }
  };
  auto epi_ab = [&](unsigned short* buf, const float* gbias, const float* lbias) {
#pragma unroll
    for (int nt = 0; nt < 8; ++nt) {
      int col = nt * 16 + lrow;
      float bg = gbias[col], bl = lbias[col];
      u16x4 pk;
#pragma unroll
      for (int r = 0; r < 4; ++r)
        pk[r] = f2bfi(sigm(accg[nt][r] + bg) * (accl[nt][r] + bl));
      *(u16x4*)(buf + col * 136 + wave * 16 + qk * 4) = pk;
    }
  };
  auto wout = [&](unsigned short* dst, const unsigned short* buf) {
#pragma unroll
    for (int it = 0; it < 4; ++it) {
      int idx = it * 512 + t;
      int col = idx >> 4, i = idx & 15;
      *(u16x8*)(dst + (size_t)col * MM + m0 + i * 8) = *(const u16x8*)(buf + col * 136 + i * 8);
    }
  };

#pragma unroll
  for (int ks = 0; ks < 4; ++ks)
    af[ks] = ldfrag(W0 + (wave * 16 + lrow) * 136 + ks * 32 + 8 * qk);
  stage_st(W1, rga);
  stage_ld(rgb, 256);
  bar_lds();                                                  // b1
  run_gemm(W1, accg);
  stage_st(W0, rla);
  stage_ld(rlb, 384);
  bar_lds();                                                  // b2
  run_gemm(W0, accl);
  stage_st(W1, rgb);
  stage_ld(rg, 512);
  bar_lds();                                                  // b3
  epi_ab(W0, ga_b, la_b);
  bar_lds();                                                  // b4
  wout(a_t, W0);
  run_gemm(W1, accg);
  bar_lds();                                                  // b5
  stage_st(W0, rlb);
  stage_st(W1, rg);
  bar_lds();                                                  // b6
  run_gemm(W0, accl);
  bar_lds();                                                  // b7
  epi_ab(W0, gb_b, lb_b);
  run_gemm(W1, accg);
  bar_lds();                                                  // b8
  wout(b_t, W0);
#pragma unroll
  for (int nt = 0; nt < 8; ++nt) {
    int col = nt * 16 + lrow;
    float bg = g_b[col];
#pragma unroll
    for (int r = 0; r < 4; ++r)
      W1[(wave * 16 + qk * 4 + r) * 136 + col] = f2bfi(sigm(accg[nt][r] + bg));
  }
  bar_lds();                                                  // b9
#pragma unroll
  for (int it = 0; it < 4; ++it) {
    int idx = it * 512 + t;
    int mr = idx >> 4, off = (idx & 15) * 8;
    *(u16x8*)(g_buf + (m0 + mr) * 128 + off) = *(const u16x8*)(W1 + mr * 136 + off);
  }
}

// ---------------- K2: channel-batched NT GEMM (R6 proven + lgkm-only barriers) ---------
__global__ __launch_bounds__(256) void k2_einsum(
    const unsigned short* __restrict__ a_t, const unsigned short* __restrict__ b_t,
    unsigned short* __restrict__ up_t) {
  __shared__ __align__(16) unsigned short lds[20480];
  const int t = threadIdx.x;
  const int wid = (blockIdx.x & 7) * 256 + (blockIdx.x >> 3);
  const int c = wid >> 4;
  const int i0 = ((wid >> 2) & 3) * 128, j0 = (wid & 3) * 128;
  const unsigned short* Ag = a_t + (size_t)c * MM + (size_t)i0 * 512;
  const unsigned short* Bg = b_t + (size_t)c * MM + (size_t)j0 * 512;
  const int wave = t >> 6, lane = t & 63, wr = wave >> 1, wc = wave & 1;
  const int lrow = lane & 15, qk = lane >> 4;
  const int srow = t >> 2, sq = t & 3;
  f32x4 acc[4][4];
#pragma unroll
  for (int i = 0; i < 4; ++i)
#pragma unroll
    for (int j = 0; j < 4; ++j)
#pragma unroll
      for (int r = 0; r < 4; ++r) acc[i][j][r] = 0.f;

  u16x8 ra[2], rb[2];
  auto tile_ld = [&](int k0) {
#pragma unroll
    for (int h = 0; h < 2; ++h) {
      int row = h * 64 + srow;
      ra[h] = *(const u16x8*)(Ag + (size_t)row * 512 + k0 + sq * 8);
      rb[h] = *(const u16x8*)(Bg + (size_t)row * 512 + k0 + sq * 8);
    }
  };
  auto tile_st = [&](int buf) {
    unsigned short* sA = lds + buf * 5120;
    unsigned short* sB = lds + 10240 + buf * 5120;
#pragma unroll
    for (int h = 0; h < 2; ++h) {
      int row = h * 64 + srow;
      *(u16x8*)(sA + row * 40 + sq * 8) = ra[h];
      *(u16x8*)(sB + row * 40 + sq * 8) = rb[h];
    }
  };

  tile_ld(0);
  tile_st(0);
  bar_lds();
  int cur = 0;
  for (int ks = 0; ks < 16; ++ks) {
    if (ks < 15) tile_ld((ks + 1) * 32);
    const unsigned short* sA = lds + cur * 5120;
    const unsigned short* sB = lds + 10240 + cur * 5120;
    bf16x8 afr[4], bv[4];
#pragma unroll
    for (int mt = 0; mt < 4; ++mt)
      afr[mt] = ldfrag(sA + (wr * 64 + mt * 16 + lrow) * 40 + 8 * qk);
#pragma unroll
    for (int nt = 0; nt < 4; ++nt)
      bv[nt] = ldfrag(sB + (wc * 64 + nt * 16 + lrow) * 40 + 8 * qk);
#pragma unroll
    for (int mt = 0; mt < 4; ++mt)
#pragma unroll
      for (int nt = 0; nt < 4; ++nt)
        acc[mt][nt] = __builtin_amdgcn_mfma_f32_16x16x32_bf16(afr[mt], bv[nt], acc[mt][nt], 0, 0, 0);
    if (ks < 15) tile_st(cur ^ 1);
    bar_lds();
    cur ^= 1;
  }
  unsigned short* up = up_t + (size_t)c * MM;
#pragma unroll
  for (int mt = 0; mt < 4; ++mt)
#pragma unroll
    for (int nt = 0; nt < 4; ++nt) {
      int col = j0 + wc * 64 + nt * 16 + lrow;
#pragma unroll
      for (int r = 0; r < 4; ++r) {
        int row = i0 + wr * 64 + mt * 16 + qk * 4 + r;
        up[(size_t)row * 512 + col] = f2bfi(acc[mt][nt][r]);
      }
    }
}

// ---------------- K3: LN(update) @ lu_w + lu_b, * g -> out (R6 + lgkm-only barriers) ---
__global__ __launch_bounds__(256) void k3_final(
    const unsigned short* __restrict__ up_t, const unsigned short* __restrict__ g_buf,
    const unsigned short* __restrict__ WT,
    const float* __restrict__ lnug, const float* __restrict__ lnub,
    const float* __restrict__ lu_b, float* __restrict__ out) {
  __shared__ __align__(16) unsigned short sU[64 * 138];
  __shared__ __align__(16) unsigned short sA[64 * 136];
  __shared__ __align__(16) unsigned short sB[128 * 136];
  const int t = threadIdx.x;
  const size_t m0 = (size_t)blockIdx.x * 64;
#pragma unroll
  for (int it = 0; it < 4; ++it) {
    int idx = it * 256 + t;
    int c = idx >> 3, m8 = (idx & 7) * 8;
    u16x8 v = *(const u16x8*)(up_t + (size_t)c * MM + m0 + m8);
#pragma unroll
    for (int j = 0; j < 8; ++j) sU[(m8 + j) * 138 + c] = v[j];
  }
#pragma unroll
  for (int it = 0; it < 8; ++it) {
    int idx = it * 256 + t;
    int n = idx >> 4, off = (idx & 15) * 8;
    *(u16x8*)(sB + n * 136 + off) = *(const u16x8*)(WT + (size_t)(640 + n) * 128 + off);
  }
  bar_lds();
  {
    const int row = t >> 2, q = t & 3;
    float vals[32]; float s = 0.f, ss = 0.f;
#pragma unroll
    for (int jj = 0; jj < 32; ++jj) {
      int cc = q + jj * 4;
      float x = bf2f(sU[row * 138 + cc]);
      vals[jj] = x; s += x; ss += x * x;
    }
    s += __shfl_xor(s, 1);  s += __shfl_xor(s, 2);
    ss += __shfl_xor(ss, 1); ss += __shfl_xor(ss, 2);
    float mean = s * (1.f / 128.f);
    float var  = ss * (1.f / 128.f) - mean * mean;
    float rstd = rsqrtf(var + 1e-5f);
#pragma unroll
    for (int jj = 0; jj < 32; ++jj) {
      int cc = q + jj * 4;
      float zn = (vals[jj] - mean) * rstd * lnug[cc] + lnub[cc];
      sA[row * 136 + cc] = f2bfi(zn);
    }
  }
  bar_lds();
  const int wave = t >> 6, lane = t & 63, lrow = lane & 15, qk = lane >> 4;
  f32x4 acc[8];
#pragma unroll
  for (int i = 0; i < 8; ++i)
#pragma unroll
    for (int r = 0; r < 4; ++r) acc[i][r] = 0.f;
#pragma unroll
  for (int ks = 0; ks < 4; ++ks) {
    int k0 = ks * 32;
    bf16x8 af = ldfrag(sA + (wave * 16 + lrow) * 136 + k0 + 8 * qk);
#pragma unroll
    for (int nt = 0; nt < 8; ++nt) {
      bf16x8 bv = ldfrag(sB + (nt * 16 + lrow) * 136 + k0 + 8 * qk);
      acc[nt] = __builtin_amdgcn_mfma_f32_16x16x32_bf16(af, bv, acc[nt], 0, 0, 0);
    }
  }
#pragma unroll
  for (int nt = 0; nt < 8; ++nt) {
    int e = nt * 16 + lrow;
    float bb = lu_b[e];
#pragma unroll
    for (int r = 0; r < 4; ++r) {
      size_t m = m0 + wave * 16 + qk * 4 + r;
      float lin = acc[nt][r] + bb;
      float gv = bf2f(g_buf[m * 128 + e]);
      out[m * 128 + e] = gv * lin;
    }
  }
}

extern "C" void kernel_launch(void* const* d_in, const int* in_sizes, int n_in,
                              void* d_out, int out_size, void* d_ws, size_t ws_size,
                              hipStream_t stream) {
  const float* pair = (const float*)d_in[0];
  const float* lng  = (const float*)d_in[1];
  const float* lnb  = (const float*)d_in[2];
  const float* ga_w = (const float*)d_in[3];
  const float* ga_b = (const float*)d_in[4];
  const float* la_w = (const float*)d_in[5];
  const float* la_b = (const float*)d_in[6];
  const float* gb_w = (const float*)d_in[7];
  const float* gb_b = (const float*)d_in[8];
  const float* lb_w = (const float*)d_in[9];
  const float* lb_b = (const float*)d_in[10];
  const float* g_w  = (const float*)d_in[11];
  const float* g_b  = (const float*)d_in[12];
  const float* lnug = (const float*)d_in[13];
  const float* lnub = (const float*)d_in[14];
  const float* lu_w = (const float*)d_in[15];
  const float* lu_b = (const float*)d_in[16];
  float* out = (float*)d_out;

  char* ws = (char*)d_ws;
  unsigned short* WT    = (unsigned short*)(ws);                  // 196608 B
  unsigned short* a_t   = (unsigned short*)(ws + 196608ull);      // 128*M*2
  unsigned short* b_t   = (unsigned short*)(ws + 67305472ull);    // 128*M*2
  unsigned short* g_buf = (unsigned short*)(ws + 134414336ull);   // M*128*2
  unsigned short* up_t  = (unsigned short*)(ws + 201523200ull);   // 128*M*2

  hipLaunchKernelGGL(prep_weights, dim3(384), dim3(256), 0, stream,
                     ga_w, la_w, gb_w, lb_w, g_w, lu_w, WT);
  hipLaunchKernelGGL(k1_proj, dim3(2048), dim3(512), 0, stream,
                     pair, lng, lnb, WT, ga_b, la_b, gb_b, lb_b, g_b, a_t, b_t, g_buf);
  hipLaunchKernelGGL(k2_einsum, dim3(2048), dim3(256), 0, stream, a_t, b_t, up_t);
  hipLaunchKernelGGL(k3_final, dim3(4096), dim3(256), 0, stream,
                     up_t, g_buf, WT, lnug, lnub, lu_b, out);
}

// Round 13
// 278.150 us; speedup vs baseline: 1.2252x; 1.0125x over previous
//
#include <hip/hip_runtime.h>
#include <hip/hip_bf16.h>

#define NN 512
#define MM (NN*NN)   // 262144 rows

typedef __attribute__((ext_vector_type(8))) unsigned short u16x8;
typedef __attribute__((ext_vector_type(4))) unsigned short u16x4;
typedef __attribute__((ext_vector_type(8))) __bf16 bf16x8;
typedef __attribute__((ext_vector_type(4))) float f32x4;

static __device__ __forceinline__ unsigned short f2bfi(float f) {
  return __builtin_bit_cast(unsigned short, __float2bfloat16(f));
}
static __device__ __forceinline__ float bf2f(unsigned short h) {
  return __uint_as_float(((unsigned int)h) << 16);
}
static __device__ __forceinline__ bf16x8 ldfrag(const unsigned short* p) {
  u16x8 v = *(const u16x8*)p;
  return __builtin_bit_cast(bf16x8, v);
}
static __device__ __forceinline__ float sigm(float x) {
  return __builtin_amdgcn_rcpf(1.0f + __expf(-x));
}
// LDS-only barrier: drains ds ops (lgkmcnt) but leaves global loads/stores in flight.
static __device__ __forceinline__ void bar_lds() {
  asm volatile("s_waitcnt lgkmcnt(0)" ::: "memory");
  __builtin_amdgcn_s_barrier();
}

// ---------------- prep: WT[n][k] (bf16), n: [ga|la|gb|lb|g|lu] x 128 cols, k = 128 ----
__global__ void prep_weights(const float* __restrict__ ga_w, const float* __restrict__ la_w,
                             const float* __restrict__ gb_w, const float* __restrict__ lb_w,
                             const float* __restrict__ g_w,  const float* __restrict__ lu_w,
                             unsigned short* __restrict__ WT) {
  int idx = blockIdx.x * 256 + threadIdx.x;
  if (idx >= 768 * 128) return;
  int n = idx >> 7;
  int k = idx & 127;
  int grp = n >> 7, cn = n & 127;
  const float* tabs[6] = {ga_w, la_w, gb_w, lb_w, g_w, lu_w};
  WT[idx] = f2bfi(tabs[grp][k * 128 + cn]);
}

// ---------------- K1: fused LN + 5 projections (R12 config, unchanged) -----------------
__global__ __launch_bounds__(512, 4) void k1_proj(
    const float* __restrict__ pair, const float* __restrict__ lng, const float* __restrict__ lnb,
    const unsigned short* __restrict__ WT,
    const float* __restrict__ ga_b, const float* __restrict__ la_b,
    const float* __restrict__ gb_b, const float* __restrict__ lb_b,
    const float* __restrict__ g_b,
    unsigned short* __restrict__ a_t, unsigned short* __restrict__ b_t,
    unsigned short* __restrict__ g_buf) {
  __shared__ __align__(16) unsigned short W0[128 * 136];
  __shared__ __align__(16) unsigned short W1[128 * 136];
  const int t = threadIdx.x;
  const size_t m0 = (size_t)blockIdx.x * 128;
  const int wave = t >> 6, lane = t & 63, lrow = lane & 15, qk = lane >> 4;
  const int rbase = t >> 4, off_ = (t & 15) * 8;

  u16x8 rga[4], rla[4], rgb[4], rlb[4], rg[4];
  auto stage_ld = [&](u16x8* r, int base) {
#pragma unroll
    for (int it = 0; it < 4; ++it)
      r[it] = *(const u16x8*)(WT + (size_t)(base + it * 32 + rbase) * 128 + off_);
  };
  auto stage_st = [&](unsigned short* buf, const u16x8* r) {
#pragma unroll
    for (int it = 0; it < 4; ++it)
      *(u16x8*)(buf + (it * 32 + rbase) * 136 + off_) = r[it];
  };

  stage_ld(rga, 0);
  stage_ld(rla, 128);

  {
    const int row = t >> 2, q = t & 3;
    const float* pr = pair + (m0 + row) * 128 + q * 32;
    float vals[32];
    float s = 0.f, ss = 0.f;
#pragma unroll
    for (int it = 0; it < 8; ++it) {
      f32x4 v = *(const f32x4*)(pr + it * 4);
#pragma unroll
      for (int j = 0; j < 4; ++j) { float x = v[j]; vals[it * 4 + j] = x; s += x; ss += x * x; }
    }
    s += __shfl_xor(s, 1);  s += __shfl_xor(s, 2);
    ss += __shfl_xor(ss, 1); ss += __shfl_xor(ss, 2);
    const float mean = s * (1.f / 128.f);
    const float var  = ss * (1.f / 128.f) - mean * mean;
    const float rstd = rsqrtf(var + 1e-5f);
#pragma unroll
    for (int i = 0; i < 4; ++i) {
      u16x8 pk;
#pragma unroll
      for (int j = 0; j < 8; ++j) {
        int c = q * 32 + i * 8 + j;
        pk[j] = f2bfi((vals[i * 8 + j] - mean) * rstd * lng[c] + lnb[c]);
      }
      *(u16x8*)(W0 + row * 136 + q * 32 + i * 8) = pk;
    }
  }
  bar_lds();                                                  // b0

  bf16x8 af[4];
  f32x4 accg[8], accl[8];
  auto run_gemm = [&](const unsigned short* buf, f32x4* acc) {
#pragma unroll
    for (int nt = 0; nt < 8; ++nt)
#pragma unroll
      for (int r = 0; r < 4; ++r) acc[nt][r] = 0.f;
#pragma unroll
    for (int ks = 0; ks < 4; ++ks)
#pragma unroll
      for (int nt = 0; nt < 8; ++nt) {
        bf16x8 bv = ldfrag(buf + (nt * 16 + lrow) * 136 + ks * 32 + 8 * qk);
        acc[nt] = __builtin_amdgcn_mfma_f32_16x16x32_bf16(af[ks], bv, acc[nt], 0, 0, 0);
      }
  };
  auto epi_ab = [&](unsigned short* buf, const float* gbias, const float* lbias) {
#pragma unroll
    for (int nt = 0; nt < 8; ++nt) {
      int col = nt * 16 + lrow;
      float bg = gbias[col], bl = lbias[col];
      u16x4 pk;
#pragma unroll
      for (int r = 0; r < 4; ++r)
        pk[r] = f2bfi(sigm(accg[nt][r] + bg) * (accl[nt][r] + bl));
      *(u16x4*)(buf + col * 136 + wave * 16 + qk * 4) = pk;
    }
  };
  auto wout = [&](unsigned short* dst, const unsigned short* buf) {
#pragma unroll
    for (int it = 0; it < 4; ++it) {
      int idx = it * 512 + t;
      int col = idx >> 4, i = idx & 15;
      *(u16x8*)(dst + (size_t)col * MM + m0 + i * 8) = *(const u16x8*)(buf + col * 136 + i * 8);
    }
  };

#pragma unroll
  for (int ks = 0; ks < 4; ++ks)
    af[ks] = ldfrag(W0 + (wave * 16 + lrow) * 136 + ks * 32 + 8 * qk);
  stage_st(W1, rga);
  stage_ld(rgb, 256);
  bar_lds();                                                  // b1
  run_gemm(W1, accg);
  stage_st(W0, rla);
  stage_ld(rlb, 384);
  bar_lds();                                                  // b2
  run_gemm(W0, accl);
  stage_st(W1, rgb);
  stage_ld(rg, 512);
  bar_lds();                                                  // b3
  epi_ab(W0, ga_b, la_b);
  bar_lds();                                                  // b4
  wout(a_t, W0);
  run_gemm(W1, accg);
  bar_lds();                                                  // b5
  stage_st(W0, rlb);
  stage_st(W1, rg);
  bar_lds();                                                  // b6
  run_gemm(W0, accl);
  bar_lds();                                                  // b7
  epi_ab(W0, gb_b, lb_b);
  run_gemm(W1, accg);
  bar_lds();                                                  // b8
  wout(b_t, W0);
#pragma unroll
  for (int nt = 0; nt < 8; ++nt) {
    int col = nt * 16 + lrow;
    float bg = g_b[col];
#pragma unroll
    for (int r = 0; r < 4; ++r)
      W1[(wave * 16 + qk * 4 + r) * 136 + col] = f2bfi(sigm(accg[nt][r] + bg));
  }
  bar_lds();                                                  // b9
#pragma unroll
  for (int it = 0; it < 4; ++it) {
    int idx = it * 512 + t;
    int mr = idx >> 4, off = (idx & 15) * 8;
    *(u16x8*)(g_buf + (m0 + mr) * 128 + off) = *(const u16x8*)(W1 + mr * 136 + off);
  }
}

// ---------------- K2: channel-batched NT GEMM, 256x256 tiles, (512,2) ------------------
// grid 512 = 128 channels x 4 tiles (2x2 of 256); 64 consecutive wids per XCD = 16 ch.
// Single-buffered 40KB LDS; next k-tile prefetched to regs under the 32-MFMA cluster.
__global__ __launch_bounds__(512, 2) void k2_einsum(
    const unsigned short* __restrict__ a_t, const unsigned short* __restrict__ b_t,
    unsigned short* __restrict__ up_t) {
  __shared__ __align__(16) unsigned short sA[256 * 40];
  __shared__ __align__(16) unsigned short sB[256 * 40];
  const int t = threadIdx.x;
  const int wid = (blockIdx.x & 7) * 64 + (blockIdx.x >> 3);
  const int c = wid >> 2;
  const int i0 = ((wid >> 1) & 1) * 256, j0 = (wid & 1) * 256;
  const unsigned short* Ag = a_t + (size_t)c * MM + (size_t)i0 * 512;
  const unsigned short* Bg = b_t + (size_t)c * MM + (size_t)j0 * 512;
  const int wave = t >> 6, lane = t & 63, wr = wave >> 2, wc = wave & 3;
  const int lrow = lane & 15, qk = lane >> 4;
  const int srow = t >> 2, sq = t & 3;   // staging: rows srow, srow+128; k-octet sq
  f32x4 acc[8][4];
#pragma unroll
  for (int i = 0; i < 8; ++i)
#pragma unroll
    for (int j = 0; j < 4; ++j)
#pragma unroll
      for (int r = 0; r < 4; ++r) acc[i][j][r] = 0.f;

  u16x8 ra[2], rb[2];
  auto tile_ld = [&](int k0) {
#pragma unroll
    for (int h = 0; h < 2; ++h) {
      int row = h * 128 + srow;
      ra[h] = *(const u16x8*)(Ag + (size_t)row * 512 + k0 + sq * 8);
      rb[h] = *(const u16x8*)(Bg + (size_t)row * 512 + k0 + sq * 8);
    }
  };
  auto tile_st = [&]() {
#pragma unroll
    for (int h = 0; h < 2; ++h) {
      int row = h * 128 + srow;
      *(u16x8*)(sA + row * 40 + sq * 8) = ra[h];
      *(u16x8*)(sB + row * 40 + sq * 8) = rb[h];
    }
  };

  tile_ld(0);
  tile_st();
  bar_lds();
  for (int ks = 0; ks < 16; ++ks) {
    if (ks < 15) tile_ld((ks + 1) * 32);      // prefetch flies under MFMAs
    bf16x8 af[8], bv[4];
#pragma unroll
    for (int mt = 0; mt < 8; ++mt)
      af[mt] = ldfrag(sA + (wr * 128 + mt * 16 + lrow) * 40 + 8 * qk);
#pragma unroll
    for (int nt = 0; nt < 4; ++nt)
      bv[nt] = ldfrag(sB + (wc * 64 + nt * 16 + lrow) * 40 + 8 * qk);
#pragma unroll
    for (int mt = 0; mt < 8; ++mt)
#pragma unroll
      for (int nt = 0; nt < 4; ++nt)
        acc[mt][nt] = __builtin_amdgcn_mfma_f32_16x16x32_bf16(af[mt], bv[nt], acc[mt][nt], 0, 0, 0);
    bar_lds();                                // compute on sA/sB done
    if (ks < 15) {
      tile_st();
      bar_lds();                              // new tile visible
    }
  }
  unsigned short* up = up_t + (size_t)c * MM;
#pragma unroll
  for (int mt = 0; mt < 8; ++mt)
#pragma unroll
    for (int nt = 0; nt < 4; ++nt) {
      int col = j0 + wc * 64 + nt * 16 + lrow;
#pragma unroll
      for (int r = 0; r < 4; ++r) {
        int row = i0 + wr * 128 + mt * 16 + qk * 4 + r;
        up[(size_t)row * 512 + col] = f2bfi(acc[mt][nt][r]);
      }
    }
}

// ---------------- K3: LN(update) @ lu_w + lu_b, * g -> out (R12, unchanged) ------------
__global__ __launch_bounds__(256) void k3_final(
    const unsigned short* __restrict__ up_t, const unsigned short* __restrict__ g_buf,
    const unsigned short* __restrict__ WT,
    const float* __restrict__ lnug, const float* __restrict__ lnub,
    const float* __restrict__ lu_b, float* __restrict__ out) {
  __shared__ __align__(16) unsigned short sU[64 * 138];
  __shared__ __align__(16) unsigned short sA[64 * 136];
  __shared__ __align__(16) unsigned short sB[128 * 136];
  const int t = threadIdx.x;
  const size_t m0 = (size_t)blockIdx.x * 64;
#pragma unroll
  for (int it = 0; it < 4; ++it) {
    int idx = it * 256 + t;
    int c = idx >> 3, m8 = (idx & 7) * 8;
    u16x8 v = *(const u16x8*)(up_t + (size_t)c * MM + m0 + m8);
#pragma unroll
    for (int j = 0; j < 8; ++j) sU[(m8 + j) * 138 + c] = v[j];
  }
#pragma unroll
  for (int it = 0; it < 8; ++it) {
    int idx = it * 256 + t;
    int n = idx >> 4, off = (idx & 15) * 8;
    *(u16x8*)(sB + n * 136 + off) = *(const u16x8*)(WT + (size_t)(640 + n) * 128 + off);
  }
  bar_lds();
  {
    const int row = t >> 2, q = t & 3;
    float vals[32]; float s = 0.f, ss = 0.f;
#pragma unroll
    for (int jj = 0; jj < 32; ++jj) {
      int cc = q + jj * 4;
      float x = bf2f(sU[row * 138 + cc]);
      vals[jj] = x; s += x; ss += x * x;
    }
    s += __shfl_xor(s, 1);  s += __shfl_xor(s, 2);
    ss += __shfl_xor(ss, 1); ss += __shfl_xor(ss, 2);
    float mean = s * (1.f / 128.f);
    float var  = ss * (1.f / 128.f) - mean * mean;
    float rstd = rsqrtf(var + 1e-5f);
#pragma unroll
    for (int jj = 0; jj < 32; ++jj) {
      int cc = q + jj * 4;
      float zn = (vals[jj] - mean) * rstd * lnug[cc] + lnub[cc];
      sA[row * 136 + cc] = f2bfi(zn);
    }
  }
  bar_lds();
  const int wave = t >> 6, lane = t & 63, lrow = lane & 15, qk = lane >> 4;
  f32x4 acc[8];
#pragma unroll
  for (int i = 0; i < 8; ++i)
#pragma unroll
    for (int r = 0; r < 4; ++r) acc[i][r] = 0.f;
#pragma unroll
  for (int ks = 0; ks < 4; ++ks) {
    int k0 = ks * 32;
    bf16x8 af = ldfrag(sA + (wave * 16 + lrow) * 136 + k0 + 8 * qk);
#pragma unroll
    for (int nt = 0; nt < 8; ++nt) {
      bf16x8 bv = ldfrag(sB + (nt * 16 + lrow) * 136 + k0 + 8 * qk);
      acc[nt] = __builtin_amdgcn_mfma_f32_16x16x32_bf16(af, bv, acc[nt], 0, 0, 0);
    }
  }
#pragma unroll
  for (int nt = 0; nt < 8; ++nt) {
    int e = nt * 16 + lrow;
    float bb = lu_b[e];
#pragma unroll
    for (int r = 0; r < 4; ++r) {
      size_t m = m0 + wave * 16 + qk * 4 + r;
      float lin = acc[nt][r] + bb;
      float gv = bf2f(g_buf[m * 128 + e]);
      out[m * 128 + e] = gv * lin;
    }
  }
}

extern "C" void kernel_launch(void* const* d_in, const int* in_sizes, int n_in,
                              void* d_out, int out_size, void* d_ws, size_t ws_size,
                              hipStream_t stream) {
  const float* pair = (const float*)d_in[0];
  const float* lng  = (const float*)d_in[1];
  const float* lnb  = (const float*)d_in[2];
  const float* ga_w = (const float*)d_in[3];
  const float* ga_b = (const float*)d_in[4];
  const float* la_w = (const float*)d_in[5];
  const float* la_b = (const float*)d_in[6];
  const float* gb_w = (const float*)d_in[7];
  const float* gb_b = (const float*)d_in[8];
  const float* lb_w = (const float*)d_in[9];
  const float* lb_b = (const float*)d_in[10];
  const float* g_w  = (const float*)d_in[11];
  const float* g_b  = (const float*)d_in[12];
  const float* lnug = (const float*)d_in[13];
  const float* lnub = (const float*)d_in[14];
  const float* lu_w = (const float*)d_in[15];
  const float* lu_b = (const float*)d_in[16];
  float* out = (float*)d_out;

  char* ws = (char*)d_ws;
  unsigned short* WT    = (unsigned short*)(ws);                  // 196608 B
  unsigned short* a_t   = (unsigned short*)(ws + 196608ull);      // 128*M*2
  unsigned short* b_t   = (unsigned short*)(ws + 67305472ull);    // 128*M*2
  unsigned short* g_buf = (unsigned short*)(ws + 134414336ull);   // M*128*2
  unsigned short* up_t  = (unsigned short*)(ws + 201523200ull);   // 128*M*2

  hipLaunchKernelGGL(prep_weights, dim3(384), dim3(256), 0, stream,
                     ga_w, la_w, gb_w, lb_w, g_w, lu_w, WT);
  hipLaunchKernelGGL(k1_proj, dim3(2048), dim3(512), 0, stream,
                     pair, lng, lnb, WT, ga_b, la_b, gb_b, lb_b, g_b, a_t, b_t, g_buf);
  hipLaunchKernelGGL(k2_einsum, dim3(512), dim3(512), 0, stream, a_t, b_t, up_t);
  hipLaunchKernelGGL(k3_final, dim3(4096), dim3(256), 0, stream,
                     up_t, g_buf, WT, lnug, lnub, lu_b, out);
}